// Round 1
// baseline (4393.232 us; speedup 1.0000x reference)
//
#include <hip/hip_runtime.h>

#define N_NODES 100000
#define E_EDGES 1600000
#define D_FEAT 64
#define H_FEAT 64
#define L_LAYERS 3
#define G_GRAPHS 128
#define OUT_F 10
#define BN_EPS 1e-5f

// -------------------- edge scatter: agg[dst] += x[src] --------------------
// 16 threads per edge, each handles 4 consecutive floats (float4 gather,
// 4 scalar HW f32 atomics). 16 lanes cover one 256B row-segment -> coalesced.
__global__ __launch_bounds__(256) void scatter_kernel(
    const float* __restrict__ x, const int* __restrict__ src,
    const int* __restrict__ dst, float* __restrict__ agg) {
    int idx = blockIdx.x * blockDim.x + threadIdx.x;      // < E*16 = 25.6M
    if (idx >= E_EDGES * 16) return;
    int e = idx >> 4;
    int c = (idx & 15) << 2;
    int s = src[e];
    int d = dst[e];
    float4 v = *reinterpret_cast<const float4*>(x + (size_t)s * 64 + c);
    float* p = agg + (size_t)d * 64 + c;
    unsafeAtomicAdd(p + 0, v.x);
    unsafeAtomicAdd(p + 1, v.y);
    unsafeAtomicAdd(p + 2, v.z);
    unsafeAtomicAdd(p + 3, v.w);
}

// -------------------- GEMM1 + BN stats: h = (x + agg) @ W1 + b1 ----------
// block = 256 threads, 64 rows per block. W1 and A staged in LDS.
// thread (c = tid&63, rowgroup = tid>>6) computes 16 outputs of column c.
__global__ __launch_bounds__(256) void gemm1_bn_kernel(
    const float* __restrict__ xin, const float* __restrict__ agg,
    const float* __restrict__ W1, const float* __restrict__ b1,
    float* __restrict__ h, float* __restrict__ stats) {
    __shared__ float sA[64][64];
    __shared__ float sW[64][64];
    __shared__ float red[512];
    int tid = threadIdx.x;
    int row0 = blockIdx.x * 64;

    for (int i = tid; i < 1024; i += 256)
        reinterpret_cast<float4*>(&sW[0][0])[i] = reinterpret_cast<const float4*>(W1)[i];

    for (int i = tid; i < 1024; i += 256) {
        int r = i >> 4;
        int gr = row0 + r;
        float4 a = make_float4(0.f, 0.f, 0.f, 0.f);
        if (gr < N_NODES) {
            float4 xv = reinterpret_cast<const float4*>(xin)[gr * 16 + (i & 15)];
            float4 av = reinterpret_cast<const float4*>(agg)[gr * 16 + (i & 15)];
            a = make_float4(xv.x + av.x, xv.y + av.y, xv.z + av.z, xv.w + av.w);
        }
        reinterpret_cast<float4*>(&sA[0][0])[i] = a;
    }
    __syncthreads();

    int c = tid & 63;
    int rbase = (tid >> 6) * 16;
    float bias = b1[c];
    float lsum = 0.f, lsq = 0.f;
    for (int i = 0; i < 16; ++i) {
        int r = rbase + i;
        int gr = row0 + r;
        float acc = bias;
        #pragma unroll
        for (int k = 0; k < 64; ++k) acc += sA[r][k] * sW[k][c];
        if (gr < N_NODES) {
            h[(size_t)gr * 64 + c] = acc;
            lsum += acc;
            lsq += acc * acc;
        }
    }
    red[tid] = lsum;
    red[256 + tid] = lsq;
    __syncthreads();
    if (tid < 64) {
        float s = red[tid] + red[tid + 64] + red[tid + 128] + red[tid + 192];
        float q = red[256 + tid] + red[256 + tid + 64] + red[256 + tid + 128] + red[256 + tid + 192];
        unsafeAtomicAdd(&stats[tid], s);
        unsafeAtomicAdd(&stats[64 + tid], q);
    }
}

// -------------------- BN finalize: stats -> scale/shift ------------------
__global__ void bn_final_kernel(float* __restrict__ stats,
                                const float* __restrict__ gamma,
                                const float* __restrict__ beta) {
    int c = threadIdx.x;  // 64 threads
    float mu = stats[c] * (1.0f / N_NODES);
    float var = stats[64 + c] * (1.0f / N_NODES) - mu * mu;
    float scale = gamma[c] * rsqrtf(var + BN_EPS);
    float shift = beta[c] - mu * scale;
    stats[c] = scale;
    stats[64 + c] = shift;
}

// ------ GEMM2 + pool: xn = relu(h*scale+shift) @ W2 + b2 ; pooled += xn ---
// in-place on h (rows staged to LDS before overwrite). batch sorted ->
// run-length-compressed atomics into pooled.
__global__ __launch_bounds__(256) void gemm2_pool_kernel(
    float* __restrict__ h, const float* __restrict__ stats,
    const float* __restrict__ W2, const float* __restrict__ b2,
    const int* __restrict__ batch, float* __restrict__ pooled) {
    __shared__ float sA[64][64];
    __shared__ float sW[64][64];
    __shared__ int sB[64];
    int tid = threadIdx.x;
    int row0 = blockIdx.x * 64;

    for (int i = tid; i < 1024; i += 256)
        reinterpret_cast<float4*>(&sW[0][0])[i] = reinterpret_cast<const float4*>(W2)[i];

    for (int i = tid; i < 1024; i += 256) {
        int r = i >> 4;
        int gr = row0 + r;
        float4 a = make_float4(0.f, 0.f, 0.f, 0.f);
        if (gr < N_NODES) {
            float4 hv = reinterpret_cast<const float4*>(h)[gr * 16 + (i & 15)];
            int c0 = (i & 15) << 2;
            a.x = fmaxf(fmaf(hv.x, stats[c0 + 0], stats[64 + c0 + 0]), 0.f);
            a.y = fmaxf(fmaf(hv.y, stats[c0 + 1], stats[64 + c0 + 1]), 0.f);
            a.z = fmaxf(fmaf(hv.z, stats[c0 + 2], stats[64 + c0 + 2]), 0.f);
            a.w = fmaxf(fmaf(hv.w, stats[c0 + 3], stats[64 + c0 + 3]), 0.f);
        }
        reinterpret_cast<float4*>(&sA[0][0])[i] = a;
    }
    if (tid < 64) {
        int gr = row0 + tid;
        sB[tid] = (gr < N_NODES) ? batch[gr] : -1;
    }
    __syncthreads();

    int c = tid & 63;
    int rbase = (tid >> 6) * 16;
    float bias = b2[c];
    float pacc = 0.f;
    int curb = -1;
    for (int i = 0; i < 16; ++i) {
        int r = rbase + i;
        int gr = row0 + r;
        float acc = bias;
        #pragma unroll
        for (int k = 0; k < 64; ++k) acc += sA[r][k] * sW[k][c];
        if (gr < N_NODES) {
            h[(size_t)gr * 64 + c] = acc;
            int b = sB[r];
            if (b != curb) {
                if (curb >= 0) unsafeAtomicAdd(&pooled[curb * 64 + c], pacc);
                curb = b;
                pacc = 0.f;
            }
            pacc += acc;
        }
    }
    if (curb >= 0) unsafeAtomicAdd(&pooled[curb * 64 + c], pacc);
}

// -------------------- output: score += pooled @ Wout + bout --------------
__global__ void out_kernel(const float* __restrict__ pooled,
                           const float* __restrict__ Wout,
                           const float* __restrict__ bout,
                           float* __restrict__ score) {
    int idx = blockIdx.x * blockDim.x + threadIdx.x;
    if (idx >= G_GRAPHS * OUT_F) return;
    int g = idx / OUT_F;
    int o = idx - g * OUT_F;
    float acc = bout[o];
    #pragma unroll
    for (int k = 0; k < 64; ++k) acc += pooled[g * 64 + k] * Wout[k * OUT_F + o];
    score[idx] += acc;
}

extern "C" void kernel_launch(void* const* d_in, const int* in_sizes, int n_in,
                              void* d_out, int out_size, void* d_ws, size_t ws_size,
                              hipStream_t stream) {
    const float* x     = (const float*)d_in[0];
    const int*   ei    = (const int*)d_in[1];
    const int*   batch = (const int*)d_in[2];
    const float* W1    = (const float*)d_in[3];
    const float* b1    = (const float*)d_in[4];
    const float* gamma = (const float*)d_in[5];
    const float* beta  = (const float*)d_in[6];
    const float* W2    = (const float*)d_in[7];
    const float* b2    = (const float*)d_in[8];
    const float* Wout  = (const float*)d_in[9];
    const float* bout  = (const float*)d_in[10];
    float* out = (float*)d_out;

    float* AGG    = (float*)d_ws;                      // N*64
    float* H      = AGG + (size_t)N_NODES * 64;        // N*64
    float* stats  = H + (size_t)N_NODES * 64;          // 128
    float* pooled = stats + 128;                       // G*64

    const int* src = ei;
    const int* dst = ei + E_EDGES;

    hipMemsetAsync(d_out, 0, (size_t)G_GRAPHS * OUT_F * sizeof(float), stream);

    int nb = (N_NODES + 63) / 64;
    int scatter_blocks = (E_EDGES * 16 + 255) / 256;

    for (int l = 0; l < L_LAYERS; ++l) {
        const float* xin = (l == 0) ? x : H;
        hipMemsetAsync(AGG, 0, (size_t)N_NODES * 64 * sizeof(float), stream);
        hipMemsetAsync(stats, 0, 128 * sizeof(float), stream);
        hipMemsetAsync(pooled, 0, (size_t)G_GRAPHS * 64 * sizeof(float), stream);

        scatter_kernel<<<scatter_blocks, 256, 0, stream>>>(xin, src, dst, AGG);
        gemm1_bn_kernel<<<nb, 256, 0, stream>>>(xin, AGG, W1 + l * 64 * 64, b1 + l * 64, H, stats);
        bn_final_kernel<<<1, 64, 0, stream>>>(stats, gamma + l * 64, beta + l * 64);
        gemm2_pool_kernel<<<nb, 256, 0, stream>>>(H, stats, W2 + l * 64 * 64, b2 + l * 64, batch, pooled);
        out_kernel<<<(G_GRAPHS * OUT_F + 127) / 128, 128, 0, stream>>>(
            pooled, Wout + l * 64 * OUT_F, bout + l * OUT_F, out);
    }
}

// Round 2
// 952.381 us; speedup vs baseline: 4.6129x; 4.6129x over previous
//
#include <hip/hip_runtime.h>

#define N_NODES 100000
#define E_EDGES 1600000
#define D_FEAT 64
#define H_FEAT 64
#define L_LAYERS 3
#define G_GRAPHS 128
#define OUT_F 10
#define BN_EPS 1e-5f
#define SCAN_T 1024
#define SCAN_CHUNK ((N_NODES + SCAN_T - 1) / SCAN_T)

// -------------------- CSR build: degree histogram ------------------------
__global__ __launch_bounds__(256) void deg_kernel(const int* __restrict__ dst,
                                                  int* __restrict__ deg) {
    int e = blockIdx.x * blockDim.x + threadIdx.x;
    if (e < E_EDGES) atomicAdd(&deg[dst[e]], 1);
}

// -------------------- CSR build: exclusive scan (single block) -----------
__global__ __launch_bounds__(SCAN_T) void scan_kernel(
    const int* __restrict__ deg, int* __restrict__ rowptr,
    int* __restrict__ cursor) {
    __shared__ int part[SCAN_T];
    int tid = threadIdx.x;
    int c0 = tid * SCAN_CHUNK;
    int s = 0;
    for (int i = 0; i < SCAN_CHUNK; ++i) {
        int idx = c0 + i;
        if (idx < N_NODES) s += deg[idx];
    }
    part[tid] = s;
    __syncthreads();
    for (int off = 1; off < SCAN_T; off <<= 1) {
        int v = (tid >= off) ? part[tid - off] : 0;
        __syncthreads();
        part[tid] += v;
        __syncthreads();
    }
    int run = (tid == 0) ? 0 : part[tid - 1];
    for (int i = 0; i < SCAN_CHUNK; ++i) {
        int idx = c0 + i;
        if (idx < N_NODES) {
            rowptr[idx] = run;
            cursor[idx] = run;
            run += deg[idx];
        }
    }
    if (tid == SCAN_T - 1) rowptr[N_NODES] = part[SCAN_T - 1];
}

// -------------------- CSR build: bucket fill -----------------------------
__global__ __launch_bounds__(256) void fill_kernel(
    const int* __restrict__ src, const int* __restrict__ dst,
    int* __restrict__ cursor, int* __restrict__ nbr) {
    int e = blockIdx.x * blockDim.x + threadIdx.x;
    if (e < E_EDGES) {
        int pos = atomicAdd(&cursor[dst[e]], 1);
        nbr[pos] = src[e];
    }
}

// ------------- gather-aggregate: agg[i] = x[i] + sum_j x[nbr[j]] ---------
// 16 threads per node row, each owns one float4 (coalesced 256B/row).
__global__ __launch_bounds__(256) void gather_kernel(
    const float* __restrict__ x, const int* __restrict__ rowptr,
    const int* __restrict__ nbr, float* __restrict__ agg) {
    int idx = blockIdx.x * blockDim.x + threadIdx.x;   // N*16 threads
    int row = idx >> 4;
    if (row >= N_NODES) return;
    int c = idx & 15;
    float4 acc = reinterpret_cast<const float4*>(x)[row * 16 + c];
    int beg = rowptr[row], end = rowptr[row + 1];
    for (int j = beg; j < end; ++j) {
        int s = nbr[j];
        float4 v = reinterpret_cast<const float4*>(x)[s * 16 + c];
        acc.x += v.x; acc.y += v.y; acc.z += v.z; acc.w += v.w;
    }
    reinterpret_cast<float4*>(agg)[row * 16 + c] = acc;
}

// -------------------- GEMM1 + BN stats: h = agg @ W1 + b1 ----------------
__global__ __launch_bounds__(256) void gemm1_bn_kernel(
    const float* __restrict__ agg, const float* __restrict__ W1,
    const float* __restrict__ b1, float* __restrict__ h,
    float* __restrict__ stats) {
    __shared__ float sA[64][64];
    __shared__ float sW[64][64];
    __shared__ float red[512];
    int tid = threadIdx.x;
    int row0 = blockIdx.x * 64;

    for (int i = tid; i < 1024; i += 256)
        reinterpret_cast<float4*>(&sW[0][0])[i] = reinterpret_cast<const float4*>(W1)[i];

    for (int i = tid; i < 1024; i += 256) {
        int r = i >> 4;
        int gr = row0 + r;
        float4 a = make_float4(0.f, 0.f, 0.f, 0.f);
        if (gr < N_NODES)
            a = reinterpret_cast<const float4*>(agg)[gr * 16 + (i & 15)];
        reinterpret_cast<float4*>(&sA[0][0])[i] = a;
    }
    __syncthreads();

    int c = tid & 63;
    int rbase = (tid >> 6) * 16;
    float bias = b1[c];
    float lsum = 0.f, lsq = 0.f;
    for (int i = 0; i < 16; ++i) {
        int r = rbase + i;
        int gr = row0 + r;
        float acc = bias;
        #pragma unroll
        for (int k = 0; k < 64; ++k) acc += sA[r][k] * sW[k][c];
        if (gr < N_NODES) {
            h[(size_t)gr * 64 + c] = acc;
            lsum += acc;
            lsq += acc * acc;
        }
    }
    red[tid] = lsum;
    red[256 + tid] = lsq;
    __syncthreads();
    if (tid < 64) {
        float s = red[tid] + red[tid + 64] + red[tid + 128] + red[tid + 192];
        float q = red[256 + tid] + red[256 + tid + 64] + red[256 + tid + 128] + red[256 + tid + 192];
        unsafeAtomicAdd(&stats[tid], s);
        unsafeAtomicAdd(&stats[64 + tid], q);
    }
}

// -------------------- BN finalize: stats -> scale/shift ------------------
__global__ void bn_final_kernel(float* __restrict__ stats,
                                const float* __restrict__ gamma,
                                const float* __restrict__ beta) {
    int c = threadIdx.x;  // 64 threads
    float mu = stats[c] * (1.0f / N_NODES);
    float var = stats[64 + c] * (1.0f / N_NODES) - mu * mu;
    float scale = gamma[c] * rsqrtf(var + BN_EPS);
    float shift = beta[c] - mu * scale;
    stats[c] = scale;
    stats[64 + c] = shift;
}

// ------ GEMM2 + pool: xn = relu(h*scale+shift) @ W2 + b2 ; pooled += xn ---
__global__ __launch_bounds__(256) void gemm2_pool_kernel(
    float* __restrict__ h, const float* __restrict__ stats,
    const float* __restrict__ W2, const float* __restrict__ b2,
    const int* __restrict__ batch, float* __restrict__ pooled) {
    __shared__ float sA[64][64];
    __shared__ float sW[64][64];
    __shared__ int sB[64];
    int tid = threadIdx.x;
    int row0 = blockIdx.x * 64;

    for (int i = tid; i < 1024; i += 256)
        reinterpret_cast<float4*>(&sW[0][0])[i] = reinterpret_cast<const float4*>(W2)[i];

    for (int i = tid; i < 1024; i += 256) {
        int r = i >> 4;
        int gr = row0 + r;
        float4 a = make_float4(0.f, 0.f, 0.f, 0.f);
        if (gr < N_NODES) {
            float4 hv = reinterpret_cast<const float4*>(h)[gr * 16 + (i & 15)];
            int c0 = (i & 15) << 2;
            a.x = fmaxf(fmaf(hv.x, stats[c0 + 0], stats[64 + c0 + 0]), 0.f);
            a.y = fmaxf(fmaf(hv.y, stats[c0 + 1], stats[64 + c0 + 1]), 0.f);
            a.z = fmaxf(fmaf(hv.z, stats[c0 + 2], stats[64 + c0 + 2]), 0.f);
            a.w = fmaxf(fmaf(hv.w, stats[c0 + 3], stats[64 + c0 + 3]), 0.f);
        }
        reinterpret_cast<float4*>(&sA[0][0])[i] = a;
    }
    if (tid < 64) {
        int gr = row0 + tid;
        sB[tid] = (gr < N_NODES) ? batch[gr] : -1;
    }
    __syncthreads();

    int c = tid & 63;
    int rbase = (tid >> 6) * 16;
    float bias = b2[c];
    float pacc = 0.f;
    int curb = -1;
    for (int i = 0; i < 16; ++i) {
        int r = rbase + i;
        int gr = row0 + r;
        float acc = bias;
        #pragma unroll
        for (int k = 0; k < 64; ++k) acc += sA[r][k] * sW[k][c];
        if (gr < N_NODES) {
            h[(size_t)gr * 64 + c] = acc;
            int b = sB[r];
            if (b != curb) {
                if (curb >= 0) unsafeAtomicAdd(&pooled[curb * 64 + c], pacc);
                curb = b;
                pacc = 0.f;
            }
            pacc += acc;
        }
    }
    if (curb >= 0) unsafeAtomicAdd(&pooled[curb * 64 + c], pacc);
}

// -------------------- output: score += pooled @ Wout + bout --------------
__global__ void out_kernel(const float* __restrict__ pooled,
                           const float* __restrict__ Wout,
                           const float* __restrict__ bout,
                           float* __restrict__ score) {
    int idx = blockIdx.x * blockDim.x + threadIdx.x;
    if (idx >= G_GRAPHS * OUT_F) return;
    int g = idx / OUT_F;
    int o = idx - g * OUT_F;
    float acc = bout[o];
    #pragma unroll
    for (int k = 0; k < 64; ++k) acc += pooled[g * 64 + k] * Wout[k * OUT_F + o];
    score[idx] += acc;
}

extern "C" void kernel_launch(void* const* d_in, const int* in_sizes, int n_in,
                              void* d_out, int out_size, void* d_ws, size_t ws_size,
                              hipStream_t stream) {
    const float* x     = (const float*)d_in[0];
    const int*   ei    = (const int*)d_in[1];
    const int*   batch = (const int*)d_in[2];
    const float* W1    = (const float*)d_in[3];
    const float* b1    = (const float*)d_in[4];
    const float* gamma = (const float*)d_in[5];
    const float* beta  = (const float*)d_in[6];
    const float* W2    = (const float*)d_in[7];
    const float* b2    = (const float*)d_in[8];
    const float* Wout  = (const float*)d_in[9];
    const float* bout  = (const float*)d_in[10];
    float* out = (float*)d_out;

    float* AGG    = (float*)d_ws;                      // N*64
    float* H      = AGG + (size_t)N_NODES * 64;        // N*64
    float* stats  = H + (size_t)N_NODES * 64;          // 128
    float* pooled = stats + 128;                       // G*64
    int*   deg    = (int*)(pooled + (size_t)G_GRAPHS * 64);  // N
    int*   rowptr = deg + N_NODES;                     // N+1
    int*   cursor = rowptr + N_NODES + 1;              // N
    int*   nbr    = cursor + N_NODES;                  // E

    const int* src = ei;
    const int* dst = ei + E_EDGES;

    hipMemsetAsync(d_out, 0, (size_t)G_GRAPHS * OUT_F * sizeof(float), stream);
    hipMemsetAsync(deg, 0, (size_t)N_NODES * sizeof(int), stream);

    int eb = (E_EDGES + 255) / 256;
    deg_kernel<<<eb, 256, 0, stream>>>(dst, deg);
    scan_kernel<<<1, SCAN_T, 0, stream>>>(deg, rowptr, cursor);
    fill_kernel<<<eb, 256, 0, stream>>>(src, dst, cursor, nbr);

    int nb = (N_NODES + 63) / 64;
    int gatherb = (N_NODES * 16 + 255) / 256;

    for (int l = 0; l < L_LAYERS; ++l) {
        const float* xin = (l == 0) ? x : H;
        hipMemsetAsync(stats, 0, 128 * sizeof(float), stream);
        hipMemsetAsync(pooled, 0, (size_t)G_GRAPHS * 64 * sizeof(float), stream);

        gather_kernel<<<gatherb, 256, 0, stream>>>(xin, rowptr, nbr, AGG);
        gemm1_bn_kernel<<<nb, 256, 0, stream>>>(AGG, W1 + l * 64 * 64, b1 + l * 64, H, stats);
        bn_final_kernel<<<1, 64, 0, stream>>>(stats, gamma + l * 64, beta + l * 64);
        gemm2_pool_kernel<<<nb, 256, 0, stream>>>(H, stats, W2 + l * 64 * 64, b2 + l * 64, batch, pooled);
        out_kernel<<<(G_GRAPHS * OUT_F + 127) / 128, 128, 0, stream>>>(
            pooled, Wout + l * 64 * OUT_F, bout + l * OUT_F, out);
    }
}

// Round 3
// 707.130 us; speedup vs baseline: 6.2128x; 1.3468x over previous
//
#include <hip/hip_runtime.h>

#define N_NODES 100000
#define E_EDGES 1600000
#define D_FEAT 64
#define H_FEAT 64
#define L_LAYERS 3
#define G_GRAPHS 128
#define OUT_F 10
#define BN_EPS 1e-5f

#define NB4 (N_NODES / 4)                 // 25000 int4 chunks
#define SCAN_BLOCKS ((NB4 + 255) / 256)   // 98

// -------------------- CSR build: degree histogram ------------------------
__global__ __launch_bounds__(256) void deg_kernel(const int* __restrict__ dst,
                                                  int* __restrict__ deg) {
    int e = blockIdx.x * blockDim.x + threadIdx.x;
    if (e < E_EDGES) atomicAdd(&deg[dst[e]], 1);
}

// -------------------- scan phase A: per-block sums -----------------------
__global__ __launch_bounds__(256) void scanA_kernel(const int* __restrict__ deg,
                                                    int* __restrict__ bsum) {
    __shared__ int red[256];
    int t = threadIdx.x;
    int i4 = blockIdx.x * 256 + t;
    int s = 0;
    if (i4 < NB4) {
        int4 v = reinterpret_cast<const int4*>(deg)[i4];
        s = v.x + v.y + v.z + v.w;
    }
    red[t] = s;
    __syncthreads();
    for (int off = 128; off > 0; off >>= 1) {
        if (t < off) red[t] += red[t + off];
        __syncthreads();
    }
    if (t == 0) bsum[blockIdx.x] = red[0];
}

// -------------------- scan phase B: scan the block sums ------------------
__global__ __launch_bounds__(128) void scanB_kernel(int* __restrict__ bsum,
                                                    int* __restrict__ rowptr) {
    __shared__ int p[128];
    int t = threadIdx.x;
    int v = (t < SCAN_BLOCKS) ? bsum[t] : 0;
    p[t] = v;
    __syncthreads();
    for (int off = 1; off < 128; off <<= 1) {
        int u = (t >= off) ? p[t - off] : 0;
        __syncthreads();
        p[t] += u;
        __syncthreads();
    }
    if (t < SCAN_BLOCKS) bsum[t] = p[t] - v;      // exclusive block offset
    if (t == 127) rowptr[N_NODES] = p[127];       // total
}

// -------------------- scan phase C: write rowptr + cursor ----------------
__global__ __launch_bounds__(256) void scanC_kernel(
    const int* __restrict__ deg, const int* __restrict__ bsum,
    int* __restrict__ rowptr, int* __restrict__ cursor) {
    __shared__ int ts[256];
    int t = threadIdx.x;
    int i4 = blockIdx.x * 256 + t;
    int4 v = make_int4(0, 0, 0, 0);
    if (i4 < NB4) v = reinterpret_cast<const int4*>(deg)[i4];
    int s = v.x + v.y + v.z + v.w;
    ts[t] = s;
    __syncthreads();
    for (int off = 1; off < 256; off <<= 1) {
        int u = (t >= off) ? ts[t - off] : 0;
        __syncthreads();
        ts[t] += u;
        __syncthreads();
    }
    if (i4 < NB4) {
        int base = bsum[blockIdx.x] + ts[t] - s;   // exclusive prefix
        int4 rp;
        rp.x = base;
        rp.y = rp.x + v.x;
        rp.z = rp.y + v.y;
        rp.w = rp.z + v.z;
        reinterpret_cast<int4*>(rowptr)[i4] = rp;
        reinterpret_cast<int4*>(cursor)[i4] = rp;
    }
}

// -------------------- CSR build: bucket fill -----------------------------
__global__ __launch_bounds__(256) void fill_kernel(
    const int* __restrict__ src, const int* __restrict__ dst,
    int* __restrict__ cursor, int* __restrict__ nbr) {
    int e = blockIdx.x * blockDim.x + threadIdx.x;
    if (e < E_EDGES) {
        int pos = atomicAdd(&cursor[dst[e]], 1);
        nbr[pos] = src[e];
    }
}

// ------------- gather-aggregate: agg[i] = x[i] + sum_j x[nbr[j]] ---------
__global__ __launch_bounds__(256) void gather_kernel(
    const float* __restrict__ x, const int* __restrict__ rowptr,
    const int* __restrict__ nbr, float* __restrict__ agg) {
    int idx = blockIdx.x * blockDim.x + threadIdx.x;   // N*16 threads
    int row = idx >> 4;
    if (row >= N_NODES) return;
    int c = idx & 15;
    float4 acc = reinterpret_cast<const float4*>(x)[row * 16 + c];
    int beg = rowptr[row], end = rowptr[row + 1];
    for (int j = beg; j < end; ++j) {
        int s = nbr[j];
        float4 v = reinterpret_cast<const float4*>(x)[s * 16 + c];
        acc.x += v.x; acc.y += v.y; acc.z += v.z; acc.w += v.w;
    }
    reinterpret_cast<float4*>(agg)[row * 16 + c] = acc;
}

// -------------------- GEMM1 + BN stats: h = agg @ W1 + b1 ----------------
__global__ __launch_bounds__(256) void gemm1_bn_kernel(
    const float* __restrict__ agg, const float* __restrict__ W1,
    const float* __restrict__ b1, float* __restrict__ h,
    float* __restrict__ stats) {
    __shared__ float sA[64][64];
    __shared__ float sW[64][64];
    __shared__ float red[512];
    int tid = threadIdx.x;
    int row0 = blockIdx.x * 64;

    for (int i = tid; i < 1024; i += 256)
        reinterpret_cast<float4*>(&sW[0][0])[i] = reinterpret_cast<const float4*>(W1)[i];

    for (int i = tid; i < 1024; i += 256) {
        int r = i >> 4;
        int gr = row0 + r;
        float4 a = make_float4(0.f, 0.f, 0.f, 0.f);
        if (gr < N_NODES)
            a = reinterpret_cast<const float4*>(agg)[gr * 16 + (i & 15)];
        reinterpret_cast<float4*>(&sA[0][0])[i] = a;
    }
    __syncthreads();

    int c = tid & 63;
    int rbase = (tid >> 6) * 16;
    float bias = b1[c];
    float lsum = 0.f, lsq = 0.f;
    for (int i = 0; i < 16; ++i) {
        int r = rbase + i;
        int gr = row0 + r;
        float acc = bias;
        #pragma unroll
        for (int k = 0; k < 64; ++k) acc += sA[r][k] * sW[k][c];
        if (gr < N_NODES) {
            h[(size_t)gr * 64 + c] = acc;
            lsum += acc;
            lsq += acc * acc;
        }
    }
    red[tid] = lsum;
    red[256 + tid] = lsq;
    __syncthreads();
    if (tid < 64) {
        float s = red[tid] + red[tid + 64] + red[tid + 128] + red[tid + 192];
        float q = red[256 + tid] + red[256 + tid + 64] + red[256 + tid + 128] + red[256 + tid + 192];
        unsafeAtomicAdd(&stats[tid], s);
        unsafeAtomicAdd(&stats[64 + tid], q);
    }
}

// -------------------- BN finalize: stats -> scale/shift ------------------
__global__ void bn_final_kernel(float* __restrict__ stats,
                                const float* __restrict__ gamma,
                                const float* __restrict__ beta) {
    int c = threadIdx.x;  // 64 threads
    float mu = stats[c] * (1.0f / N_NODES);
    float var = stats[64 + c] * (1.0f / N_NODES) - mu * mu;
    float scale = gamma[c] * rsqrtf(var + BN_EPS);
    float shift = beta[c] - mu * scale;
    stats[c] = scale;
    stats[64 + c] = shift;
}

// ------ GEMM2 + pool: xn = relu(h*scale+shift) @ W2 + b2 ; pooled += xn ---
__global__ __launch_bounds__(256) void gemm2_pool_kernel(
    float* __restrict__ h, const float* __restrict__ stats,
    const float* __restrict__ W2, const float* __restrict__ b2,
    const int* __restrict__ batch, float* __restrict__ pooled) {
    __shared__ float sA[64][64];
    __shared__ float sW[64][64];
    __shared__ int sB[64];
    int tid = threadIdx.x;
    int row0 = blockIdx.x * 64;

    for (int i = tid; i < 1024; i += 256)
        reinterpret_cast<float4*>(&sW[0][0])[i] = reinterpret_cast<const float4*>(W2)[i];

    for (int i = tid; i < 1024; i += 256) {
        int r = i >> 4;
        int gr = row0 + r;
        float4 a = make_float4(0.f, 0.f, 0.f, 0.f);
        if (gr < N_NODES) {
            float4 hv = reinterpret_cast<const float4*>(h)[gr * 16 + (i & 15)];
            int c0 = (i & 15) << 2;
            a.x = fmaxf(fmaf(hv.x, stats[c0 + 0], stats[64 + c0 + 0]), 0.f);
            a.y = fmaxf(fmaf(hv.y, stats[c0 + 1], stats[64 + c0 + 1]), 0.f);
            a.z = fmaxf(fmaf(hv.z, stats[c0 + 2], stats[64 + c0 + 2]), 0.f);
            a.w = fmaxf(fmaf(hv.w, stats[c0 + 3], stats[64 + c0 + 3]), 0.f);
        }
        reinterpret_cast<float4*>(&sA[0][0])[i] = a;
    }
    if (tid < 64) {
        int gr = row0 + tid;
        sB[tid] = (gr < N_NODES) ? batch[gr] : -1;
    }
    __syncthreads();

    int c = tid & 63;
    int rbase = (tid >> 6) * 16;
    float bias = b2[c];
    float pacc = 0.f;
    int curb = -1;
    for (int i = 0; i < 16; ++i) {
        int r = rbase + i;
        int gr = row0 + r;
        float acc = bias;
        #pragma unroll
        for (int k = 0; k < 64; ++k) acc += sA[r][k] * sW[k][c];
        if (gr < N_NODES) {
            h[(size_t)gr * 64 + c] = acc;
            int b = sB[r];
            if (b != curb) {
                if (curb >= 0) unsafeAtomicAdd(&pooled[curb * 64 + c], pacc);
                curb = b;
                pacc = 0.f;
            }
            pacc += acc;
        }
    }
    if (curb >= 0) unsafeAtomicAdd(&pooled[curb * 64 + c], pacc);
}

// -------------------- output: score += pooled @ Wout + bout --------------
__global__ void out_kernel(const float* __restrict__ pooled,
                           const float* __restrict__ Wout,
                           const float* __restrict__ bout,
                           float* __restrict__ score) {
    int idx = blockIdx.x * blockDim.x + threadIdx.x;
    if (idx >= G_GRAPHS * OUT_F) return;
    int g = idx / OUT_F;
    int o = idx - g * OUT_F;
    float acc = bout[o];
    #pragma unroll
    for (int k = 0; k < 64; ++k) acc += pooled[g * 64 + k] * Wout[k * OUT_F + o];
    score[idx] += acc;
}

extern "C" void kernel_launch(void* const* d_in, const int* in_sizes, int n_in,
                              void* d_out, int out_size, void* d_ws, size_t ws_size,
                              hipStream_t stream) {
    const float* x     = (const float*)d_in[0];
    const int*   ei    = (const int*)d_in[1];
    const int*   batch = (const int*)d_in[2];
    const float* W1    = (const float*)d_in[3];
    const float* b1    = (const float*)d_in[4];
    const float* gamma = (const float*)d_in[5];
    const float* beta  = (const float*)d_in[6];
    const float* W2    = (const float*)d_in[7];
    const float* b2    = (const float*)d_in[8];
    const float* Wout  = (const float*)d_in[9];
    const float* bout  = (const float*)d_in[10];
    float* out = (float*)d_out;

    float* AGG    = (float*)d_ws;                            // N*64
    float* H      = AGG + (size_t)N_NODES * 64;              // N*64
    float* stats  = H + (size_t)N_NODES * 64;                // 128
    float* pooled = stats + 128;                             // G*64
    int*   deg    = (int*)(pooled + (size_t)G_GRAPHS * 64);  // N
    int*   rowptr = deg + N_NODES;                           // N+4 (padded, 16B-aligned)
    int*   cursor = rowptr + N_NODES + 4;                    // N
    int*   nbr    = cursor + N_NODES;                        // E
    int*   bsum   = nbr + E_EDGES;                           // SCAN_BLOCKS

    const int* src = ei;
    const int* dst = ei + E_EDGES;

    hipMemsetAsync(d_out, 0, (size_t)G_GRAPHS * OUT_F * sizeof(float), stream);
    hipMemsetAsync(deg, 0, (size_t)N_NODES * sizeof(int), stream);

    int eb = (E_EDGES + 255) / 256;
    deg_kernel<<<eb, 256, 0, stream>>>(dst, deg);
    scanA_kernel<<<SCAN_BLOCKS, 256, 0, stream>>>(deg, bsum);
    scanB_kernel<<<1, 128, 0, stream>>>(bsum, rowptr);
    scanC_kernel<<<SCAN_BLOCKS, 256, 0, stream>>>(deg, bsum, rowptr, cursor);
    fill_kernel<<<eb, 256, 0, stream>>>(src, dst, cursor, nbr);

    int nb = (N_NODES + 63) / 64;
    int gatherb = (N_NODES * 16 + 255) / 256;

    for (int l = 0; l < L_LAYERS; ++l) {
        const float* xin = (l == 0) ? x : H;
        hipMemsetAsync(stats, 0, 128 * sizeof(float), stream);
        hipMemsetAsync(pooled, 0, (size_t)G_GRAPHS * 64 * sizeof(float), stream);

        gather_kernel<<<gatherb, 256, 0, stream>>>(xin, rowptr, nbr, AGG);
        gemm1_bn_kernel<<<nb, 256, 0, stream>>>(AGG, W1 + l * 64 * 64, b1 + l * 64, H, stats);
        bn_final_kernel<<<1, 64, 0, stream>>>(stats, gamma + l * 64, beta + l * 64);
        gemm2_pool_kernel<<<nb, 256, 0, stream>>>(H, stats, W2 + l * 64 * 64, b2 + l * 64, batch, pooled);
        out_kernel<<<(G_GRAPHS * OUT_F + 127) / 128, 128, 0, stream>>>(
            pooled, Wout + l * 64 * OUT_F, bout + l * OUT_F, out);
    }
}